// Round 5
// baseline (814.641 us; speedup 1.0000x reference)
//
#include <hip/hip_runtime.h>

// PlatonicConv: linear attention with tetrahedral-group RoPE.
// N=32768 nodes, C=E=384, G=12 groups, H=1, D=32, P=16, 64 graphs (batch sorted).
// I/O: ALL fp32 (round-1 NaN proved fp32 inputs; round-2/3/4's absmax == sqrt(2)*max|ref|
// was exactly the signature of bf16-written/fp32-decoded output -> output is fp32).
// Internally bf16 MFMA with fp32 accumulate (harness threshold is 2% of max|ref|).
//
// Pipeline:
//  prep_wt  : Wq/Wv/Wo fp32 -> bf16 transposed (WqT, WvT, WoT)
//  gemm_bt  : Q = x @ Wq + bq -> ws (bf16)
//  4x { gemm_bt: V chunk -> VO (bf16) ; kv_chunk: atomics into KV (fp32) }
//  4x { attn_chunk: O chunk -> VO (bf16) ; gemm_bt: out rows = O @ Wo + bo -> d_out (fp32) }
//
// MFMA C/D mapping (col=lane&15, row=(lane>>4)*4+r) HW-confirmed by round-4 probe.

#define N_NODES 32768
#define K_DIM   384
#define P_PAIR  16
#define NUM_GRAPHS 64
#define CHUNK   8192

typedef unsigned short u16;
typedef __bf16 bf16x8 __attribute__((ext_vector_type(8)));
typedef float  f32x4  __attribute__((ext_vector_type(4)));

__device__ __forceinline__ u16 f2bf(float f) {
    unsigned int i = __float_as_uint(f);
    unsigned int r = i + 0x7FFFu + ((i >> 16) & 1u);   // RNE
    return (u16)(r >> 16);
}
__device__ __forceinline__ float bf2f(u16 u) {
    union { unsigned int i; float f; } x;
    x.i = ((unsigned int)u) << 16;
    return x.f;
}
__device__ __forceinline__ int lbound(const int* __restrict__ a, int n, int v) {
    int lo = 0, hi = n;
    while (lo < hi) { int m = (lo + hi) >> 1; if (a[m] < v) lo = m + 1; else hi = m; }
    return lo;
}

// ---------------------------------------------------------------------------
// Weight transposes, fp32 -> bf16:  WT[a][b] = W[b][a]  (all 384x384)
__global__ void prep_wt(const float* __restrict__ Wq, const float* __restrict__ Wv,
                        const float* __restrict__ Wo,
                        u16* __restrict__ WqT, u16* __restrict__ WvT,
                        u16* __restrict__ WoT) {
    int idx = blockIdx.x * 256 + threadIdx.x;
    int which = idx / 147456;            // 0..2
    int j = idx - which * 147456;
    int a = j / 384, b = j % 384;
    float v;
    u16* dst;
    if (which == 0)      { v = Wq[b * 384 + a]; dst = WqT; }
    else if (which == 1) { v = Wv[b * 384 + a]; dst = WvT; }
    else                 { v = Wo[b * 384 + a]; dst = WoT; }
    dst[j] = f2bf(v);
}

// ---------------------------------------------------------------------------
// C[m][.] = A[rowOff+m][0:384] @ Bt[.][0:384]^T + bias.  128x128 tile, BK=32,
// 4 waves 2x2, each 64x64 via 4x4 16x16x32 MFMA. LDS pitch 40 u16 (80 B rows:
// 16B-aligned, 2-way bank aliasing = free).
// aFp32: A is fp32 (converted to bf16 during staging) else bf16.
// cFp32: C written fp32 else bf16. Bias always fp32.
__global__ __launch_bounds__(256) void gemm_bt(
    const void* __restrict__ A, int lda, int rowOff, int aFp32,
    const u16* __restrict__ Bt, const float* __restrict__ bias,
    void* __restrict__ Cmat, int ldc, int cFp32, int ntiles) {
    __shared__ u16 As[128 * 40];
    __shared__ u16 Bs[128 * 40];
    const int tid = threadIdx.x;
    const int bx = blockIdx.x % ntiles;
    const int by = blockIdx.x / ntiles;
    const int m0 = by << 7, n0 = bx << 7;
    const int w = tid >> 6, lane = tid & 63;
    const int wr = (w >> 1) << 6, wc = (w & 1) << 6;
    const int lm = lane & 15, q = lane >> 4;
    const int row_s = tid >> 2, c8 = (tid & 3) << 3;

    f32x4 acc[4][4];
#pragma unroll
    for (int i = 0; i < 4; i++)
#pragma unroll
        for (int j = 0; j < 4; j++)
#pragma unroll
            for (int r = 0; r < 4; r++) acc[i][j][r] = 0.0f;

    for (int k0 = 0; k0 < K_DIM; k0 += 32) {
        __syncthreads();
#pragma unroll
        for (int p = 0; p < 2; p++) {
            int row = row_s + p * 64;
            size_t abase = (size_t)(rowOff + m0 + row) * lda + k0 + c8;
            if (aFp32) {
                const float* Af = (const float*)A;
                float4 a0 = *reinterpret_cast<const float4*>(Af + abase);
                float4 a1 = *reinterpret_cast<const float4*>(Af + abase + 4);
                union { u16 u[8]; float4 v; } pk;
                pk.u[0] = f2bf(a0.x); pk.u[1] = f2bf(a0.y);
                pk.u[2] = f2bf(a0.z); pk.u[3] = f2bf(a0.w);
                pk.u[4] = f2bf(a1.x); pk.u[5] = f2bf(a1.y);
                pk.u[6] = f2bf(a1.z); pk.u[7] = f2bf(a1.w);
                *reinterpret_cast<float4*>(&As[row * 40 + c8]) = pk.v;
            } else {
                const u16* Au = (const u16*)A;
                *reinterpret_cast<float4*>(&As[row * 40 + c8]) =
                    *reinterpret_cast<const float4*>(Au + abase);
            }
            *reinterpret_cast<float4*>(&Bs[row * 40 + c8]) =
                *reinterpret_cast<const float4*>(Bt + (size_t)(n0 + row) * K_DIM + k0 + c8);
        }
        __syncthreads();
        bf16x8 af[4], bfr[4];
#pragma unroll
        for (int i = 0; i < 4; i++) {
            af[i]  = *reinterpret_cast<const bf16x8*>(&As[(wr + i * 16 + lm) * 40 + q * 8]);
            bfr[i] = *reinterpret_cast<const bf16x8*>(&Bs[(wc + i * 16 + lm) * 40 + q * 8]);
        }
#pragma unroll
        for (int i = 0; i < 4; i++)
#pragma unroll
            for (int j = 0; j < 4; j++)
                acc[i][j] = __builtin_amdgcn_mfma_f32_16x16x32_bf16(af[i], bfr[j], acc[i][j], 0, 0, 0);
    }

    // C/D layout: col = lane&15, row = (lane>>4)*4 + r   [HW-confirmed, round-4 probe]
#pragma unroll
    for (int j = 0; j < 4; j++) {
        int gc = n0 + wc + j * 16 + lm;
        float bs = bias[gc];
#pragma unroll
        for (int i = 0; i < 4; i++) {
            int gr = m0 + wr + i * 16 + q * 4;
            if (cFp32) {
                float* Cf = (float*)Cmat;
#pragma unroll
                for (int r = 0; r < 4; r++)
                    Cf[(size_t)(gr + r) * ldc + gc] = acc[i][j][r] + bs;
            } else {
                u16* Cu = (u16*)Cmat;
#pragma unroll
                for (int r = 0; r < 4; r++)
                    Cu[(size_t)(gr + r) * ldc + gc] = f2bf(acc[i][j][r] + bs);
            }
        }
    }
}

// ---------------------------------------------------------------------------
// KV[g][grp][d][e] += (1/512) sum_{n in graph g, n in [lo,hi)} k_d(n) * v_e(n)
// Grid 256 = 64 graphs x 4 parts; 384 threads = (grp, e). V is chunk-local bf16.
__global__ __launch_bounds__(384) void kv_chunk(
    const u16* __restrict__ V, const float* __restrict__ pos,
    const int* __restrict__ batch, const float* __restrict__ freqs,
    float* __restrict__ KV, int lo, int hi) {
    const int g = blockIdx.x >> 2, part = blockIdx.x & 3;
    const int s = lbound(batch, N_NODES, g);
    const int e = lbound(batch, N_NODES, g + 1);
    const int len = e - s;
    int nb = s + (len * part) / 4;
    int ne = s + (len * (part + 1)) / 4;
    nb = max(nb, lo); ne = min(ne, hi);
    if (nb >= ne) return;
    const int t = threadIdx.x;
    const int grp = t >> 5, ec = t & 31;
    const int p = ec >> 1, sgn = ec & 1;
    const float f0 = freqs[(grp * P_PAIR + p) * 3 + 0];
    const float f1 = freqs[(grp * P_PAIR + p) * 3 + 1];
    const float f2 = freqs[(grp * P_PAIR + p) * 3 + 2];

    __shared__ float kbuf[8][384];
    float acc[32];
#pragma unroll
    for (int d = 0; d < 32; d++) acc[d] = 0.0f;

    for (int base = nb; base < ne; base += 8) {
        int cnt = min(8, ne - base);
        __syncthreads();
        for (int i = 0; i < cnt; i++) {
            int n = base + i;
            float ph = pos[n * 3 + 0] * f0 + pos[n * 3 + 1] * f1 + pos[n * 3 + 2] * f2;
            float sn, cs;
            __sincosf(ph, &sn, &cs);
            kbuf[i][t] = sgn ? (sn + cs) : (cs - sn);   // rope applied to ones
        }
        __syncthreads();
        for (int i = 0; i < cnt; i++) {
            int n = base + i;
            float vv = bf2f(V[(size_t)(n - lo) * 384 + t]);
            const float* kr = &kbuf[i][grp << 5];
#pragma unroll
            for (int d = 0; d < 32; d++) acc[d] = fmaf(kr[d], vv, acc[d]);
        }
    }
    float* dst = KV + ((g * 12 + grp) << 10) + ec;
    const float scale = 1.0f / 512.0f;
#pragma unroll
    for (int d = 0; d < 32; d++) atomicAdd(dst + (d << 5), acc[d] * scale);
}

// ---------------------------------------------------------------------------
// O[n-lo][grp*32+e] = sum_d qrot[n][grp][d] * KV[g][grp][d][e];  Q bf16 in ws.
__global__ __launch_bounds__(384) void attn_chunk(
    const u16* __restrict__ Q, const float* __restrict__ pos,
    const int* __restrict__ batch, const float* __restrict__ freqs,
    const float* __restrict__ KV, u16* __restrict__ O, int lo, int hi) {
    const int g = blockIdx.x >> 2, part = blockIdx.x & 3;
    const int s = lbound(batch, N_NODES, g);
    const int e = lbound(batch, N_NODES, g + 1);
    const int len = e - s;
    int nb = s + (len * part) / 4;
    int ne = s + (len * (part + 1)) / 4;
    nb = max(nb, lo); ne = min(ne, hi);
    if (nb >= ne) return;
    const int t = threadIdx.x;
    const int grp = t >> 5, ec = t & 31;
    const int p = ec >> 1, sgn = ec & 1;
    const float f0 = freqs[(grp * P_PAIR + p) * 3 + 0];
    const float f1 = freqs[(grp * P_PAIR + p) * 3 + 1];
    const float f2 = freqs[(grp * P_PAIR + p) * 3 + 2];

    float kv[32];
    const float* src = KV + ((g * 12 + grp) << 10) + ec;
#pragma unroll
    for (int d = 0; d < 32; d++) kv[d] = src[d << 5];

    __shared__ float qbuf[8][384];
    const int cq = t & ~1;
    for (int base = nb; base < ne; base += 8) {
        int cnt = min(8, ne - base);
        __syncthreads();
        for (int i = 0; i < cnt; i++) {
            int n = base + i;
            float qa = bf2f(Q[(size_t)n * 384 + cq]);
            float qb = bf2f(Q[(size_t)n * 384 + cq + 1]);
            float ph = pos[n * 3 + 0] * f0 + pos[n * 3 + 1] * f1 + pos[n * 3 + 2] * f2;
            float sn, cs;
            __sincosf(ph, &sn, &cs);
            qbuf[i][t] = sgn ? (qa * sn + qb * cs) : (qa * cs - qb * sn);
        }
        __syncthreads();
        for (int i = 0; i < cnt; i++) {
            int n = base + i;
            const float* qr = &qbuf[i][grp << 5];
            float o = 0.0f;
#pragma unroll
            for (int d = 0; d < 32; d++) o = fmaf(qr[d], kv[d], o);
            O[(size_t)(n - lo) * 384 + t] = f2bf(o);
        }
    }
}

// ---------------------------------------------------------------------------
extern "C" void kernel_launch(void* const* d_in, const int* in_sizes, int n_in,
                              void* d_out, int out_size, void* d_ws, size_t ws_size,
                              hipStream_t stream) {
    const float* x     = (const float*)d_in[0];
    const float* pos   = (const float*)d_in[1];
    const int*   batch = (const int*)d_in[2];
    const float* Wq    = (const float*)d_in[3];
    const float* bq    = (const float*)d_in[4];
    const float* Wv    = (const float*)d_in[5];
    const float* bv    = (const float*)d_in[6];
    const float* Wo    = (const float*)d_in[7];
    const float* bo    = (const float*)d_in[8];
    const float* fr    = (const float*)d_in[9];
    float* out = (float*)d_out;               // fp32 [N][384]

    char* ws = (char*)d_ws;                   // total use ~35.5 MB
    float* KV  = (float*)(ws);                //  3,145,728 B
    u16*   WqT = (u16*)(ws + 3145728);        //    294,912 B
    u16*   WvT = (u16*)(ws + 3440640);        //    294,912 B
    u16*   WoT = (u16*)(ws + 3735552);        //    294,912 B
    u16*   Qw  = (u16*)(ws + 4030464);        // 25,165,824 B  (N x 384 bf16)
    u16*   VO  = (u16*)(ws + 29196288);       //  6,291,456 B  (8192 x 384 bf16 chunk)

    hipMemsetAsync(KV, 0, (size_t)NUM_GRAPHS * 12 * 32 * 32 * sizeof(float), stream);
    prep_wt<<<dim3(1728), dim3(256), 0, stream>>>(Wq, Wv, Wo, WqT, WvT, WoT);
    // Q = x @ Wq + bq -> ws (bf16)
    gemm_bt<<<dim3(768), dim3(256), 0, stream>>>(x, 384, 0, 1, WqT, bq, Qw, 384, 0, 3);
    // KV accumulation in 4 chunks; V chunk lives in VO
    for (int c = 0; c < 4; c++) {
        int lo = c * CHUNK;
        gemm_bt<<<dim3(192), dim3(256), 0, stream>>>(x, 384, lo, 1, WvT, bv, VO, 384, 0, 3);
        kv_chunk<<<dim3(256), dim3(384), 0, stream>>>(VO, pos, batch, fr, KV, lo, lo + CHUNK);
    }
    // attention + output GEMM in 4 chunks; O chunk in VO, final rows -> d_out (fp32)
    for (int c = 0; c < 4; c++) {
        int lo = c * CHUNK;
        attn_chunk<<<dim3(256), dim3(384), 0, stream>>>(Qw, pos, batch, fr, KV, VO, lo, lo + CHUNK);
        gemm_bt<<<dim3(192), dim3(256), 0, stream>>>(VO, 384, 0, 0, WoT, bo,
                                                     out + (size_t)lo * 384, 384, 1, 3);
    }
}

// Round 6
// 267.051 us; speedup vs baseline: 3.0505x; 3.0505x over previous
//
#include <hip/hip_runtime.h>

// PlatonicConv: linear attention with tetrahedral-group RoPE.
// N=32768 nodes, C=E=384, G=12 groups, H=1, D=32, P=16, 64 graphs (batch sorted).
// I/O fp32; internal bf16 MFMA with fp32 accumulate.
//
// Round 6: kill the kv/attn latency disaster (74.5us x4, VALUBusy 2.9%, occ 4.4%):
//  - node-range partitioning (512 blocks, no lbound, flush-on-graph-change atomics)
//  - single launches for kv and attn (attn rotates Q and writes O in-place)
//  - Q+V GEMMs fused (Nout=768); V lives in d_out's dead space as bf16
// Pipeline (6 dispatches): memset KV, prep_wt, gemm_qv, kv_k, attn_k, gemm_out.

#define N_NODES 32768
#define K_DIM   384
#define P_PAIR  16
#define NUM_GRAPHS 64

typedef unsigned short u16;
typedef __bf16 bf16x8 __attribute__((ext_vector_type(8)));
typedef float  f32x4  __attribute__((ext_vector_type(4)));

__device__ __forceinline__ u16 f2bf(float f) {
    unsigned int i = __float_as_uint(f);
    unsigned int r = i + 0x7FFFu + ((i >> 16) & 1u);   // RNE
    return (u16)(r >> 16);
}
__device__ __forceinline__ float bf2f(u16 u) {
    union { unsigned int i; float f; } x;
    x.i = ((unsigned int)u) << 16;
    return x.f;
}

// ---------------------------------------------------------------------------
// WqvT[n][k] = (n<384 ? Wq[k][n] : Wv[k][n-384]); WoT[n][k] = Wo[k][n]. fp32->bf16.
__global__ void prep_wt(const float* __restrict__ Wq, const float* __restrict__ Wv,
                        const float* __restrict__ Wo,
                        u16* __restrict__ WqvT, u16* __restrict__ WoT) {
    int idx = blockIdx.x * 256 + threadIdx.x;
    if (idx < 294912) {
        int n = idx / 384, k = idx % 384;
        WqvT[idx] = f2bf(n < 384 ? Wq[k * 384 + n] : Wv[k * 384 + (n - 384)]);
    } else {
        int j = idx - 294912;                // < 147456, grid sized exactly
        int n = j / 384, k = j % 384;
        WoT[j] = f2bf(Wo[k * 384 + n]);
    }
}

// ---------------------------------------------------------------------------
// Fused Q|V projection: [Q|V] = x @ [Wq|Wv] + [bq|bv].  A fp32 (cvt in staging),
// 128x128 tile, BK=32, 4 waves 2x2, 4x4 16x16x32 MFMA, LDS pitch 40 u16.
// Column tiles 0..2 -> Qw (ws, bf16), tiles 3..5 -> Vd (d_out, bf16).
__global__ __launch_bounds__(256) void gemm_qv(
    const float* __restrict__ A,
    const u16* __restrict__ Bt,
    const float* __restrict__ bq, const float* __restrict__ bv,
    u16* __restrict__ Qw, u16* __restrict__ Vd) {
    __shared__ u16 As[128 * 40];
    __shared__ u16 Bs[128 * 40];
    const int tid = threadIdx.x;
    const int bx = blockIdx.x % 6;
    const int by = blockIdx.x / 6;
    const int m0 = by << 7, n0 = bx << 7;
    const int w = tid >> 6, lane = tid & 63;
    const int wr = (w >> 1) << 6, wc = (w & 1) << 6;
    const int lm = lane & 15, q = lane >> 4;
    const int row_s = tid >> 2, c8 = (tid & 3) << 3;

    f32x4 acc[4][4];
#pragma unroll
    for (int i = 0; i < 4; i++)
#pragma unroll
        for (int j = 0; j < 4; j++)
#pragma unroll
            for (int r = 0; r < 4; r++) acc[i][j][r] = 0.0f;

    for (int k0 = 0; k0 < K_DIM; k0 += 32) {
        __syncthreads();
#pragma unroll
        for (int p = 0; p < 2; p++) {
            int row = row_s + p * 64;
            size_t abase = (size_t)(m0 + row) * K_DIM + k0 + c8;
            float4 a0 = *reinterpret_cast<const float4*>(A + abase);
            float4 a1 = *reinterpret_cast<const float4*>(A + abase + 4);
            union { u16 u[8]; float4 v; } pk;
            pk.u[0] = f2bf(a0.x); pk.u[1] = f2bf(a0.y);
            pk.u[2] = f2bf(a0.z); pk.u[3] = f2bf(a0.w);
            pk.u[4] = f2bf(a1.x); pk.u[5] = f2bf(a1.y);
            pk.u[6] = f2bf(a1.z); pk.u[7] = f2bf(a1.w);
            *reinterpret_cast<float4*>(&As[row * 40 + c8]) = pk.v;
            *reinterpret_cast<float4*>(&Bs[row * 40 + c8]) =
                *reinterpret_cast<const float4*>(Bt + (size_t)(n0 + row) * K_DIM + k0 + c8);
        }
        __syncthreads();
        bf16x8 af[4], bfr[4];
#pragma unroll
        for (int i = 0; i < 4; i++) {
            af[i]  = *reinterpret_cast<const bf16x8*>(&As[(wr + i * 16 + lm) * 40 + q * 8]);
            bfr[i] = *reinterpret_cast<const bf16x8*>(&Bs[(wc + i * 16 + lm) * 40 + q * 8]);
        }
#pragma unroll
        for (int i = 0; i < 4; i++)
#pragma unroll
            for (int j = 0; j < 4; j++)
                acc[i][j] = __builtin_amdgcn_mfma_f32_16x16x32_bf16(af[i], bfr[j], acc[i][j], 0, 0, 0);
    }

    // C/D layout: col = lane&15, row = (lane>>4)*4 + r  [HW-confirmed round-4 probe]
    u16* Cq = (n0 < 384) ? Qw : Vd;
    const float* bias = (n0 < 384) ? bq : bv;
    const int coff = (n0 < 384) ? 0 : 384;
#pragma unroll
    for (int j = 0; j < 4; j++) {
        int gc = n0 + wc + j * 16 + lm - coff;
        float bs = bias[gc];
#pragma unroll
        for (int i = 0; i < 4; i++) {
            int gr = m0 + wr + i * 16 + q * 4;
#pragma unroll
            for (int r = 0; r < 4; r++)
                Cq[(size_t)(gr + r) * 384 + gc] = f2bf(acc[i][j][r] + bs);
        }
    }
}

// ---------------------------------------------------------------------------
// out = O @ Wo + bo, O bf16 in ws (written in-place by attn_k), out fp32.
__global__ __launch_bounds__(256) void gemm_out(
    const u16* __restrict__ A,
    const u16* __restrict__ Bt,
    const float* __restrict__ bias,
    float* __restrict__ Cmat) {
    __shared__ u16 As[128 * 40];
    __shared__ u16 Bs[128 * 40];
    const int tid = threadIdx.x;
    const int bx = blockIdx.x % 3;
    const int by = blockIdx.x / 3;
    const int m0 = by << 7, n0 = bx << 7;
    const int w = tid >> 6, lane = tid & 63;
    const int wr = (w >> 1) << 6, wc = (w & 1) << 6;
    const int lm = lane & 15, q = lane >> 4;
    const int row_s = tid >> 2, c8 = (tid & 3) << 3;

    f32x4 acc[4][4];
#pragma unroll
    for (int i = 0; i < 4; i++)
#pragma unroll
        for (int j = 0; j < 4; j++)
#pragma unroll
            for (int r = 0; r < 4; r++) acc[i][j][r] = 0.0f;

    for (int k0 = 0; k0 < K_DIM; k0 += 32) {
        __syncthreads();
#pragma unroll
        for (int p = 0; p < 2; p++) {
            int row = row_s + p * 64;
            *reinterpret_cast<float4*>(&As[row * 40 + c8]) =
                *reinterpret_cast<const float4*>(A + (size_t)(m0 + row) * K_DIM + k0 + c8);
            *reinterpret_cast<float4*>(&Bs[row * 40 + c8]) =
                *reinterpret_cast<const float4*>(Bt + (size_t)(n0 + row) * K_DIM + k0 + c8);
        }
        __syncthreads();
        bf16x8 af[4], bfr[4];
#pragma unroll
        for (int i = 0; i < 4; i++) {
            af[i]  = *reinterpret_cast<const bf16x8*>(&As[(wr + i * 16 + lm) * 40 + q * 8]);
            bfr[i] = *reinterpret_cast<const bf16x8*>(&Bs[(wc + i * 16 + lm) * 40 + q * 8]);
        }
#pragma unroll
        for (int i = 0; i < 4; i++)
#pragma unroll
            for (int j = 0; j < 4; j++)
                acc[i][j] = __builtin_amdgcn_mfma_f32_16x16x32_bf16(af[i], bfr[j], acc[i][j], 0, 0, 0);
    }

#pragma unroll
    for (int j = 0; j < 4; j++) {
        int gc = n0 + wc + j * 16 + lm;
        float bs = bias[gc];
#pragma unroll
        for (int i = 0; i < 4; i++) {
            int gr = m0 + wr + i * 16 + q * 4;
#pragma unroll
            for (int r = 0; r < 4; r++)
                Cmat[(size_t)(gr + r) * 384 + gc] = acc[i][j][r] + bs;
        }
    }
}

// ---------------------------------------------------------------------------
// KV[g][grp][d][e] += (1/512) sum_n k_d(n) v_e(n).  512 blocks x 64 nodes,
// 384 threads = (grp, e). Flush accumulator (atomics) on graph change (sorted).
__global__ __launch_bounds__(384) void kv_k(
    const u16* __restrict__ V, const float* __restrict__ pos,
    const int* __restrict__ batch, const float* __restrict__ freqs,
    float* __restrict__ KV) {
    const int nb = blockIdx.x << 6;
    const int t = threadIdx.x;
    const int grp = t >> 5, ec = t & 31;
    const int p = ec >> 1, sgn = ec & 1;
    const float f0 = freqs[(grp * P_PAIR + p) * 3 + 0];
    const float f1 = freqs[(grp * P_PAIR + p) * 3 + 1];
    const float f2 = freqs[(grp * P_PAIR + p) * 3 + 2];

    __shared__ float kbuf[8][384];
    __shared__ int gbuf[8];
    float acc[32];
#pragma unroll
    for (int d = 0; d < 32; d++) acc[d] = 0.0f;
    int gcur = batch[nb];
    const float scale = 1.0f / 512.0f;

    for (int base = nb; base < nb + 64; base += 8) {
        __syncthreads();
        if (t < 8) gbuf[t] = batch[base + t];
#pragma unroll
        for (int i = 0; i < 8; i++) {
            int n = base + i;
            float ph = pos[n * 3 + 0] * f0 + pos[n * 3 + 1] * f1 + pos[n * 3 + 2] * f2;
            float sn, cs;
            __sincosf(ph, &sn, &cs);
            kbuf[i][t] = sgn ? (sn + cs) : (cs - sn);   // rope applied to ones
        }
        __syncthreads();
#pragma unroll
        for (int i = 0; i < 8; i++) {
            int g = gbuf[i];                            // block-uniform
            if (g != gcur) {
                float* dst = KV + ((gcur * 12 + grp) << 10) + ec;
#pragma unroll
                for (int d = 0; d < 32; d++) {
                    atomicAdd(dst + (d << 5), acc[d] * scale);
                    acc[d] = 0.0f;
                }
                gcur = g;
            }
            float vv = bf2f(V[(size_t)(base + i) * 384 + t]);
            const float* kr = &kbuf[i][grp << 5];
#pragma unroll
            for (int d = 0; d < 32; d++) acc[d] = fmaf(kr[d], vv, acc[d]);
        }
    }
    float* dst = KV + ((gcur * 12 + grp) << 10) + ec;
#pragma unroll
    for (int d = 0; d < 32; d++) atomicAdd(dst + (d << 5), acc[d] * scale);
}

// ---------------------------------------------------------------------------
// O[n][grp*32+e] = sum_d qrot[n][grp][d] * KV[batch[n]][grp][d][e].
// In-place: reads Q rows, writes O over them (barrier-protected, block-exclusive).
__global__ __launch_bounds__(384) void attn_k(
    u16* __restrict__ Qw, const float* __restrict__ pos,
    const int* __restrict__ batch, const float* __restrict__ freqs,
    const float* __restrict__ KV) {
    const int nb = blockIdx.x << 6;
    const int t = threadIdx.x;
    const int grp = t >> 5, ec = t & 31;
    const int p = ec >> 1, sgn = ec & 1;
    const float f0 = freqs[(grp * P_PAIR + p) * 3 + 0];
    const float f1 = freqs[(grp * P_PAIR + p) * 3 + 1];
    const float f2 = freqs[(grp * P_PAIR + p) * 3 + 2];

    __shared__ float qbuf[8][384];
    __shared__ int gbuf[8];
    float kv[32];
    int gcur = -1;
    const int cq = t & ~1;

    for (int base = nb; base < nb + 64; base += 8) {
        __syncthreads();
        if (t < 8) gbuf[t] = batch[base + t];
#pragma unroll
        for (int i = 0; i < 8; i++) {
            int n = base + i;
            float qa = bf2f(Qw[(size_t)n * 384 + cq]);
            float qb = bf2f(Qw[(size_t)n * 384 + cq + 1]);
            float ph = pos[n * 3 + 0] * f0 + pos[n * 3 + 1] * f1 + pos[n * 3 + 2] * f2;
            float sn, cs;
            __sincosf(ph, &sn, &cs);
            qbuf[i][t] = sgn ? (qa * sn + qb * cs) : (qa * cs - qb * sn);
        }
        __syncthreads();
#pragma unroll
        for (int i = 0; i < 8; i++) {
            int g = gbuf[i];                            // block-uniform
            if (g != gcur) {
                gcur = g;
                const float* src = KV + ((g * 12 + grp) << 10) + ec;
#pragma unroll
                for (int d = 0; d < 32; d++) kv[d] = src[d << 5];
            }
            const float* qr = &qbuf[i][grp << 5];
            float o = 0.0f;
#pragma unroll
            for (int d = 0; d < 32; d++) o = fmaf(qr[d], kv[d], o);
            Qw[(size_t)(base + i) * 384 + t] = f2bf(o);
        }
    }
}

// ---------------------------------------------------------------------------
extern "C" void kernel_launch(void* const* d_in, const int* in_sizes, int n_in,
                              void* d_out, int out_size, void* d_ws, size_t ws_size,
                              hipStream_t stream) {
    const float* x     = (const float*)d_in[0];
    const float* pos   = (const float*)d_in[1];
    const int*   batch = (const int*)d_in[2];
    const float* Wq    = (const float*)d_in[3];
    const float* bq    = (const float*)d_in[4];
    const float* Wv    = (const float*)d_in[5];
    const float* bv    = (const float*)d_in[6];
    const float* Wo    = (const float*)d_in[7];
    const float* bo    = (const float*)d_in[8];
    const float* fr    = (const float*)d_in[9];
    float* out = (float*)d_out;

    char* ws = (char*)d_ws;                   // total use ~27.8 MB
    float* KV   = (float*)(ws);               //  3,145,728 B
    u16*   WqvT = (u16*)(ws + 3145728);       //    589,824 B
    u16*   WoT  = (u16*)(ws + 3735552);       //    294,912 B
    u16*   Qw   = (u16*)(ws + 4030464);       // 25,165,824 B (Q, then O in-place)
    u16*   Vd   = (u16*)d_out;                // V bf16 in d_out's dead space (25.2 of 50.3 MB)

    hipMemsetAsync(KV, 0, (size_t)NUM_GRAPHS * 12 * 32 * 32 * sizeof(float), stream);
    prep_wt<<<dim3(1728), dim3(256), 0, stream>>>(Wq, Wv, Wo, WqvT, WoT);
    gemm_qv<<<dim3(1536), dim3(256), 0, stream>>>(x, WqvT, bq, bv, Qw, Vd);
    kv_k<<<dim3(512), dim3(384), 0, stream>>>(Vd, pos, batch, fr, KV);
    attn_k<<<dim3(512), dim3(384), 0, stream>>>(Qw, pos, batch, fr, KV);
    gemm_out<<<dim3(768), dim3(256), 0, stream>>>(Qw, WoT, bo, out);
}

// Round 7
// 245.222 us; speedup vs baseline: 3.3221x; 1.0890x over previous
//
#include <hip/hip_runtime.h>

// PlatonicConv: linear attention with tetrahedral-group RoPE.
// N=32768 nodes, C=E=384, G=12 groups, H=1, D=32, P=16, 64 graphs (batch sorted).
// I/O fp32; internal bf16 MFMA with fp32 accumulate.
//
// Round 7 (from rocprof: gemm_qv 60.8us, FETCH 3x ideal, VALUBusy 30% staging tax):
//  - prep converts x -> bf16 once (xb in d_out's dead upper half)
//  - GEMMs stage via __builtin_amdgcn_global_load_lds width=16 (m97 ladder)
//  - XCD-aware block swizzle: all column-tiles of a row-tile on one XCD's L2
// Pipeline (6 dispatches): memset KV, prep, gemm_qv, kv_k, attn_k, gemm_out.

#define N_NODES 32768
#define K_DIM   384
#define P_PAIR  16
#define NUM_GRAPHS 64

typedef unsigned short u16;
typedef __bf16 bf16x8 __attribute__((ext_vector_type(8)));
typedef float  f32x4  __attribute__((ext_vector_type(4)));
typedef __attribute__((address_space(3))) void       lds_void;
typedef const __attribute__((address_space(1))) void gbl_void;

__device__ __forceinline__ u16 f2bf(float f) {
    unsigned int i = __float_as_uint(f);
    unsigned int r = i + 0x7FFFu + ((i >> 16) & 1u);   // RNE
    return (u16)(r >> 16);
}
__device__ __forceinline__ float bf2f(u16 u) {
    union { unsigned int i; float f; } x;
    x.i = ((unsigned int)u) << 16;
    return x.f;
}

// ---------------------------------------------------------------------------
// prep: xb = bf16(x) (vectorized x8); WqvT[n][k]=[Wq|Wv][k][n]; WoT[n][k]=Wo[k][n]
__global__ void prep(const float* __restrict__ x,
                     const float* __restrict__ Wq, const float* __restrict__ Wv,
                     const float* __restrict__ Wo,
                     u16* __restrict__ xb, u16* __restrict__ WqvT,
                     u16* __restrict__ WoT) {
    int b = blockIdx.x;
    if (b < 6144) {                              // 6144*256*8 = 12,582,912 = N*384
        int i = (b * 256 + threadIdx.x) * 8;
        float4 a0 = *reinterpret_cast<const float4*>(x + i);
        float4 a1 = *reinterpret_cast<const float4*>(x + i + 4);
        union { u16 u[8]; float4 v; } pk;
        pk.u[0] = f2bf(a0.x); pk.u[1] = f2bf(a0.y);
        pk.u[2] = f2bf(a0.z); pk.u[3] = f2bf(a0.w);
        pk.u[4] = f2bf(a1.x); pk.u[5] = f2bf(a1.y);
        pk.u[6] = f2bf(a1.z); pk.u[7] = f2bf(a1.w);
        *reinterpret_cast<float4*>(xb + i) = pk.v;
    } else {
        int idx = (b - 6144) * 256 + threadIdx.x;    // < 442,368 (grid exact)
        if (idx < 294912) {
            int n = idx / 384, k = idx % 384;
            WqvT[idx] = f2bf(n < 384 ? Wq[k * 384 + n] : Wv[k * 384 + (n - 384)]);
        } else {
            int j = idx - 294912;
            int n = j / 384, k = j % 384;
            WoT[j] = f2bf(Wo[k * 384 + n]);
        }
    }
}

// ---------------------------------------------------------------------------
// Shared GEMM core: 128x128 tile, BK=32, glds width-16 staging into unpadded
// 128x32 bf16 LDS tiles (A at T[0:4096], B at T[4096:8192] u16), 4 waves 2x2,
// 4x4 16x16x32 MFMA. Staging: 16 segments of 1024B; lane l of segment s covers
// row s*16 + l/4, cols (l&3)*8 -> LDS offset exactly lane*16 B (glds order).
#define GEMM_CORE(A_PTR, B_PTR)                                                  \
    __shared__ __align__(1024) u16 T[8192];                                      \
    const int tid = threadIdx.x;                                                 \
    const int w = tid >> 6, lane = tid & 63;                                     \
    const int wr = (w >> 1) << 6, wc = (w & 1) << 6;                             \
    const int lm = lane & 15, q = lane >> 4;                                     \
    const int srow = lane >> 2, sc8 = (lane & 3) << 3;                           \
    f32x4 acc[4][4];                                                             \
    _Pragma("unroll") for (int i = 0; i < 4; i++)                                \
    _Pragma("unroll") for (int j = 0; j < 4; j++)                                \
    _Pragma("unroll") for (int r = 0; r < 4; r++) acc[i][j][r] = 0.0f;           \
    for (int k0 = 0; k0 < K_DIM; k0 += 32) {                                     \
        __syncthreads();                                                         \
        _Pragma("unroll")                                                        \
        for (int s = w; s < 16; s += 4) {                                        \
            int row = ((s & 7) << 4) + srow;                                     \
            const u16* gp = ((s >> 3) ? (B_PTR) + (size_t)(n0 + row) * K_DIM     \
                                      : (A_PTR) + (size_t)(m0 + row) * K_DIM)    \
                            + k0 + sc8;                                          \
            __builtin_amdgcn_global_load_lds((gbl_void*)gp,                      \
                                             (lds_void*)&T[s << 9], 16, 0, 0);   \
        }                                                                        \
        __syncthreads();                                                         \
        bf16x8 af[4], bfr[4];                                                    \
        _Pragma("unroll") for (int i = 0; i < 4; i++) {                          \
            af[i]  = *reinterpret_cast<const bf16x8*>(&T[(wr + i * 16 + lm) * 32 + q * 8]);          \
            bfr[i] = *reinterpret_cast<const bf16x8*>(&T[4096 + (wc + i * 16 + lm) * 32 + q * 8]);   \
        }                                                                        \
        _Pragma("unroll") for (int i = 0; i < 4; i++)                            \
        _Pragma("unroll") for (int j = 0; j < 4; j++)                            \
            acc[i][j] = __builtin_amdgcn_mfma_f32_16x16x32_bf16(af[i], bfr[j], acc[i][j], 0, 0, 0);  \
    }

// ---------------------------------------------------------------------------
// [Q|V] = xb @ [Wq|Wv]^T + [bq|bv].  Swizzle: XCD owns 32 row-tiles, bx fastest.
__global__ __launch_bounds__(256) void gemm_qv(
    const u16* __restrict__ A, const u16* __restrict__ Bt,
    const float* __restrict__ bq, const float* __restrict__ bv,
    u16* __restrict__ Qw, u16* __restrict__ Vd) {
    const int b = blockIdx.x;                 // 1536 blocks
    const int xcd = b & 7, jj = b >> 3;       // jj 0..191
    const int by = xcd * 32 + jj / 6, bx = jj % 6;
    const int m0 = by << 7, n0 = bx << 7;
    GEMM_CORE(A, Bt)
    // C/D layout: col = lane&15, row = (lane>>4)*4 + r  [HW-confirmed round-4 probe]
    u16* Cq = (n0 < 384) ? Qw : Vd;
    const float* bias = (n0 < 384) ? bq : bv;
    const int coff = (n0 < 384) ? 0 : 384;
#pragma unroll
    for (int j = 0; j < 4; j++) {
        int gc = n0 + wc + j * 16 + lm - coff;
        float bs = bias[gc];
#pragma unroll
        for (int i = 0; i < 4; i++) {
            int gr = m0 + wr + i * 16 + q * 4;
#pragma unroll
            for (int r = 0; r < 4; r++)
                Cq[(size_t)(gr + r) * 384 + gc] = f2bf(acc[i][j][r] + bs);
        }
    }
}

// ---------------------------------------------------------------------------
// out = O @ Wo^T + bo (fp32 out).  O = attn output, in-place over Qw.
__global__ __launch_bounds__(256) void gemm_out(
    const u16* __restrict__ A, const u16* __restrict__ Bt,
    const float* __restrict__ bias, float* __restrict__ Cmat) {
    const int b = blockIdx.x;                 // 768 blocks
    const int xcd = b & 7, jj = b >> 3;       // jj 0..95
    const int by = xcd * 32 + jj / 3, bx = jj % 3;
    const int m0 = by << 7, n0 = bx << 7;
    GEMM_CORE(A, Bt)
#pragma unroll
    for (int j = 0; j < 4; j++) {
        int gc = n0 + wc + j * 16 + lm;
        float bs = bias[gc];
#pragma unroll
        for (int i = 0; i < 4; i++) {
            int gr = m0 + wr + i * 16 + q * 4;
#pragma unroll
            for (int r = 0; r < 4; r++)
                Cmat[(size_t)(gr + r) * 384 + gc] = acc[i][j][r] + bs;
        }
    }
}

// ---------------------------------------------------------------------------
// KV[g][grp][d][e] += (1/512) sum_n k_d(n) v_e(n).  512 blocks x 64 nodes,
// 384 threads = (grp, e). Flush accumulator (atomics) on graph change (sorted).
__global__ __launch_bounds__(384) void kv_k(
    const u16* __restrict__ V, const float* __restrict__ pos,
    const int* __restrict__ batch, const float* __restrict__ freqs,
    float* __restrict__ KV) {
    const int nb = blockIdx.x << 6;
    const int t = threadIdx.x;
    const int grp = t >> 5, ec = t & 31;
    const int p = ec >> 1, sgn = ec & 1;
    const float f0 = freqs[(grp * P_PAIR + p) * 3 + 0];
    const float f1 = freqs[(grp * P_PAIR + p) * 3 + 1];
    const float f2 = freqs[(grp * P_PAIR + p) * 3 + 2];

    __shared__ float kbuf[8][384];
    __shared__ int gbuf[8];
    float acc[32];
#pragma unroll
    for (int d = 0; d < 32; d++) acc[d] = 0.0f;
    int gcur = batch[nb];
    const float scale = 1.0f / 512.0f;

    for (int base = nb; base < nb + 64; base += 8) {
        __syncthreads();
        if (t < 8) gbuf[t] = batch[base + t];
#pragma unroll
        for (int i = 0; i < 8; i++) {
            int n = base + i;
            float ph = pos[n * 3 + 0] * f0 + pos[n * 3 + 1] * f1 + pos[n * 3 + 2] * f2;
            float sn, cs;
            __sincosf(ph, &sn, &cs);
            kbuf[i][t] = sgn ? (sn + cs) : (cs - sn);   // rope applied to ones
        }
        __syncthreads();
#pragma unroll
        for (int i = 0; i < 8; i++) {
            int g = gbuf[i];                            // block-uniform
            if (g != gcur) {
                float* dst = KV + ((gcur * 12 + grp) << 10) + ec;
#pragma unroll
                for (int d = 0; d < 32; d++) {
                    atomicAdd(dst + (d << 5), acc[d] * scale);
                    acc[d] = 0.0f;
                }
                gcur = g;
            }
            float vv = bf2f(V[(size_t)(base + i) * 384 + t]);
            const float* kr = &kbuf[i][grp << 5];
#pragma unroll
            for (int d = 0; d < 32; d++) acc[d] = fmaf(kr[d], vv, acc[d]);
        }
    }
    float* dst = KV + ((gcur * 12 + grp) << 10) + ec;
#pragma unroll
    for (int d = 0; d < 32; d++) atomicAdd(dst + (d << 5), acc[d] * scale);
}

// ---------------------------------------------------------------------------
// O[n][grp*32+e] = sum_d qrot[n][grp][d] * KV[batch[n]][grp][d][e].  In-place over Qw.
__global__ __launch_bounds__(384) void attn_k(
    u16* __restrict__ Qw, const float* __restrict__ pos,
    const int* __restrict__ batch, const float* __restrict__ freqs,
    const float* __restrict__ KV) {
    const int nb = blockIdx.x << 6;
    const int t = threadIdx.x;
    const int grp = t >> 5, ec = t & 31;
    const int p = ec >> 1, sgn = ec & 1;
    const float f0 = freqs[(grp * P_PAIR + p) * 3 + 0];
    const float f1 = freqs[(grp * P_PAIR + p) * 3 + 1];
    const float f2 = freqs[(grp * P_PAIR + p) * 3 + 2];

    __shared__ float qbuf[8][384];
    __shared__ int gbuf[8];
    float kv[32];
    int gcur = -1;
    const int cq = t & ~1;

    for (int base = nb; base < nb + 64; base += 8) {
        __syncthreads();
        if (t < 8) gbuf[t] = batch[base + t];
#pragma unroll
        for (int i = 0; i < 8; i++) {
            int n = base + i;
            float qa = bf2f(Qw[(size_t)n * 384 + cq]);
            float qb = bf2f(Qw[(size_t)n * 384 + cq + 1]);
            float ph = pos[n * 3 + 0] * f0 + pos[n * 3 + 1] * f1 + pos[n * 3 + 2] * f2;
            float sn, cs;
            __sincosf(ph, &sn, &cs);
            qbuf[i][t] = sgn ? (qa * sn + qb * cs) : (qa * cs - qb * sn);
        }
        __syncthreads();
#pragma unroll
        for (int i = 0; i < 8; i++) {
            int g = gbuf[i];                            // block-uniform
            if (g != gcur) {
                gcur = g;
                const float* src = KV + ((g * 12 + grp) << 10) + ec;
#pragma unroll
                for (int d = 0; d < 32; d++) kv[d] = src[d << 5];
            }
            const float* qr = &qbuf[i][grp << 5];
            float o = 0.0f;
#pragma unroll
            for (int d = 0; d < 32; d++) o = fmaf(qr[d], kv[d], o);
            Qw[(size_t)(base + i) * 384 + t] = f2bf(o);
        }
    }
}

// ---------------------------------------------------------------------------
extern "C" void kernel_launch(void* const* d_in, const int* in_sizes, int n_in,
                              void* d_out, int out_size, void* d_ws, size_t ws_size,
                              hipStream_t stream) {
    const float* x     = (const float*)d_in[0];
    const float* pos   = (const float*)d_in[1];
    const int*   batch = (const int*)d_in[2];
    const float* Wq    = (const float*)d_in[3];
    const float* bq    = (const float*)d_in[4];
    const float* Wv    = (const float*)d_in[5];
    const float* bv    = (const float*)d_in[6];
    const float* Wo    = (const float*)d_in[7];
    const float* bo    = (const float*)d_in[8];
    const float* fr    = (const float*)d_in[9];
    float* out = (float*)d_out;

    char* ws = (char*)d_ws;                   // total use ~29.2 MB
    float* KV   = (float*)(ws);               //  3,145,728 B
    u16*   WqvT = (u16*)(ws + 3145728);       //    589,824 B
    u16*   WoT  = (u16*)(ws + 3735552);       //    294,912 B
    u16*   Qw   = (u16*)(ws + 4030464);       // 25,165,824 B (Q, then O in-place)
    // d_out (50.3 MB fp32) doubles as scratch until gemm_out overwrites it:
    u16*   Vd   = (u16*)d_out;                // [0, 25.2 MB): V bf16
    u16*   xb   = (u16*)d_out + N_NODES * 384;// [25.2, 50.3 MB): x as bf16

    hipMemsetAsync(KV, 0, (size_t)NUM_GRAPHS * 12 * 32 * 32 * sizeof(float), stream);
    prep<<<dim3(7872), dim3(256), 0, stream>>>(x, Wq, Wv, Wo, xb, WqvT, WoT);
    gemm_qv<<<dim3(1536), dim3(256), 0, stream>>>(xb, WqvT, bq, bv, Qw, Vd);
    kv_k<<<dim3(512), dim3(384), 0, stream>>>(Vd, pos, batch, fr, KV);
    attn_k<<<dim3(512), dim3(384), 0, stream>>>(Qw, pos, batch, fr, KV);
    gemm_out<<<dim3(768), dim3(256), 0, stream>>>(Qw, WoT, bo, out);
}